// Round 8
// baseline (299.873 us; speedup 1.0000x reference)
//
#include <hip/hip_runtime.h>
#include <hip/hip_fp16.h>

// Problem constants (match reference)
#define NC 128
#define NS 2048
#define NX 256
#define NZ 512
#define NROWS (NX * NZ)      // 131072 output pixels
#define NCOLS (NS * NC)      // 262144 rhs rows
#define RUN 16               // contiguous nnz per lane
#define WAVE_NNZ (RUN * 64)  // 1024 nnz per wave
#define NSLOTS 64            // LDS row-accumulator slots per wave

// NOTE: harness passes ALL integer inputs as int32.
// NOTE (r3): nontemporal loads REGRESSED when a line was consumed by loads
//            far apart in time. Full-line per-lane consumption via adjacent
//            instructions is safe (MSHR merges in-flight same-line loads).
// NOTE (r4): too-few waves (16/CU) -> occupancy-starved. Keep >=16K waves.
// NOTE (r5): per-lane GLOBAL atomics are HBM-side RMW on 8-XCD: 10M atomics
//            -> WRITE 146MB. Sink = per-wave LDS slots (r6: WRITE 9.4MB).
// NOTE (r6): plateau ~150us = latency-bound: gathers miss L2 (table evicted
//            by read-once streams). Fix here: NT stream loads preserve L2
//            for the 2MB fp16 table.
// NOTE (r7): __builtin_nontemporal_load rejects HIP_vector_type (class) ptrs
//            -> use clang ext_vector_type aliases.

typedef float vfloat4 __attribute__((ext_vector_type(4)));
typedef int   vint4   __attribute__((ext_vector_type(4)));

struct alignas(8) Half4 { __half2 lo, hi; };

// Kernel 1: pack x (B,K,NC,NS) into fp16 rhs[j], j = s*NC + c.
__global__ void pack_rhs_kernel(const float* __restrict__ x,
                                Half4* __restrict__ rhs) {
    int j = blockIdx.x * blockDim.x + threadIdx.x;
    if (j >= NCOLS) return;
    int c = j & (NC - 1);
    int s = j >> 7;
    int base = c * NS + s;
    Half4 h;
    h.lo = __float22half2_rn(make_float2(x[base],               x[base + 1 * NC * NS]));
    h.hi = __float22half2_rn(make_float2(x[base + 2 * NC * NS], x[base + 3 * NC * NS]));
    rhs[j] = h;
}

__device__ __forceinline__ void global_flush(float* __restrict__ out, int r,
                                             float ax, float ay, float az, float aw) {
    int ix = r >> 9;          // r / NZ
    int iz = r & (NZ - 1);    // r % NZ
    int o = iz * NX + ix;     // out[b, iz, ix]
    atomicAdd(&out[0 * NROWS + o], ax);
    atomicAdd(&out[1 * NROWS + o], ay);
    atomicAdd(&out[2 * NROWS + o], az);
    atomicAdd(&out[3 * NROWS + o], aw);
}

// Kernel 2: wave owns 1024 contiguous nnz (lane: 16). NT-streams rows/cols/
// vals with aligned 16B loads (each lane fully consumes its 64B line with 4
// adjacent loads), 16 independent fp16 gathers (L2-resident table), lane-
// local segmented accumulate -> per-wave LDS slots. Epilogue: interior rows
// direct-store, 2 boundary rows global atomicAdd (out memset-0).
__global__ void __launch_bounds__(256) spmm_seg_kernel(
        const float* __restrict__ vals,
        const int* __restrict__ cols,
        const int* __restrict__ rows,
        const Half4* __restrict__ rhs,
        float* __restrict__ out,
        int nnz) {
    __shared__ float sl[4][NSLOTS][4];   // 4KB per block

    int wv   = threadIdx.x >> 6;
    int lane = threadIdx.x & 63;
    int wid  = (blockIdx.x << 2) + wv;
    int base = wid * WAVE_NNZ + lane * RUN;

    // zero this block's LDS (256 threads x 1 float4 = 4KB)
    ((float4*)sl)[threadIdx.x] = make_float4(0.f, 0.f, 0.f, 0.f);
    __syncthreads();

    // ---- stream loads: 16 nnz per lane, non-temporal (don't evict table) ----
    vfloat4 v[4];
    vint4   c4[4], r4[4];
    if (base + RUN <= nnz) {
        #pragma unroll
        for (int q = 0; q < 4; ++q) {
            v[q]  = __builtin_nontemporal_load((const vfloat4*)(vals + base + 4 * q));
            c4[q] = __builtin_nontemporal_load((const vint4*)(cols + base + 4 * q));
            r4[q] = __builtin_nontemporal_load((const vint4*)(rows + base + 4 * q));
        }
    } else {
        #pragma unroll
        for (int q = 0; q < 4; ++q) {
            #pragma unroll
            for (int k = 0; k < 4; ++k) {
                int e = base + 4 * q + k;
                int ec = e < nnz ? e : (nnz - 1);
                v[q][k]  = e < nnz ? vals[ec] : 0.f;   // v=0: contributes nothing
                c4[q][k] = cols[ec];
                r4[q][k] = rows[ec];
            }
        }
    }

    // ---- 16 independent 8B gathers (L2-resident 2MB table) ----
    Half4 g[RUN];
    #pragma unroll
    for (int q = 0; q < 4; ++q) {
        g[4 * q + 0] = rhs[c4[q][0]];
        g[4 * q + 1] = rhs[c4[q][1]];
        g[4 * q + 2] = rhs[c4[q][2]];
        g[4 * q + 3] = rhs[c4[q][3]];
    }

    int rfirst = __shfl(r4[0][0], 0);     // wave's first row
    int rlast  = __shfl(r4[3][3], 63);    // wave's last row

    // ---- lane-local segmented accumulate, flush to LDS slots ----
    int cur = r4[0][0];
    float ax = 0.f, ay = 0.f, az = 0.f, aw = 0.f;
    #pragma unroll
    for (int j = 0; j < RUN; ++j) {
        int   rj = r4[j >> 2][j & 3];
        float vj = v[j >> 2][j & 3];
        float2 lo = __half22float2(g[j].lo);
        float2 hi = __half22float2(g[j].hi);
        if (rj != cur) {                 // ~1.1 times per 16-run
            int s = cur - rfirst;
            if (s < NSLOTS) {
                atomicAdd(&sl[wv][s][0], ax);
                atomicAdd(&sl[wv][s][1], ay);
                atomicAdd(&sl[wv][s][2], az);
                atomicAdd(&sl[wv][s][3], aw);
            } else {
                global_flush(out, cur, ax, ay, az, aw);   // span overflow: ~never
            }
            ax = ay = az = aw = 0.f;
            cur = rj;
        }
        ax += vj * lo.x;
        ay += vj * lo.y;
        az += vj * hi.x;
        aw += vj * hi.y;
    }
    {
        int s = cur - rfirst;
        if (s < NSLOTS) {
            atomicAdd(&sl[wv][s][0], ax);
            atomicAdd(&sl[wv][s][1], ay);
            atomicAdd(&sl[wv][s][2], az);
            atomicAdd(&sl[wv][s][3], aw);
        } else {
            global_flush(out, cur, ax, ay, az, aw);
        }
    }

    __syncthreads();

    // ---- epilogue: one slot per lane ----
    int span = rlast - rfirst;
    if (lane <= span && lane < NSLOTS) {
        float bx = sl[wv][lane][0];
        float by = sl[wv][lane][1];
        float bz = sl[wv][lane][2];
        float bw = sl[wv][lane][3];
        int rr = rfirst + lane;
        int ix = rr >> 9;
        int iz = rr & (NZ - 1);
        int o = iz * NX + ix;
        if (lane == 0 || rr == rlast) {
            // boundary row: may be shared with neighbor wave
            atomicAdd(&out[0 * NROWS + o], bx);
            atomicAdd(&out[1 * NROWS + o], by);
            atomicAdd(&out[2 * NROWS + o], bz);
            atomicAdd(&out[3 * NROWS + o], bw);
        } else {
            // interior row: all its nnz are in this wave (rows sorted)
            out[0 * NROWS + o] = bx;
            out[1 * NROWS + o] = by;
            out[2 * NROWS + o] = bz;
            out[3 * NROWS + o] = bw;
        }
    }
}

// Fallback (workspace too small): inline bounds + direct fp32 gather from x.
__global__ void __launch_bounds__(256) spmm_direct_kernel(
        const float* __restrict__ x,
        const float* __restrict__ vals,
        const int* __restrict__ rows,
        const int* __restrict__ cols,
        int nnz,
        float* __restrict__ out) {
    int r = (blockIdx.x << 2) + (threadIdx.x >> 6);
    int lane = threadIdx.x & 63;
    int start, end;
    {
        int lo = 0, hi = nnz;
        while (lo < hi) { int mid = (lo + hi) >> 1; if (rows[mid] < r) lo = mid + 1; else hi = mid; }
        start = lo;
        hi = nnz;
        int key = r + 1;
        while (lo < hi) { int mid = (lo + hi) >> 1; if (rows[mid] < key) lo = mid + 1; else hi = mid; }
        end = lo;
    }
    float4 acc = {0.f, 0.f, 0.f, 0.f};
    for (int i = start + lane; i < end; i += 64) {
        float v = vals[i];
        int col = cols[i];
        int cc = col & (NC - 1);
        int ss = col >> 7;
        int b = cc * NS + ss;
        acc.x += v * x[b];
        acc.y += v * x[b + 1 * NC * NS];
        acc.z += v * x[b + 2 * NC * NS];
        acc.w += v * x[b + 3 * NC * NS];
    }
    #pragma unroll
    for (int off = 32; off >= 1; off >>= 1) {
        acc.x += __shfl_xor(acc.x, off, 64);
        acc.y += __shfl_xor(acc.y, off, 64);
        acc.z += __shfl_xor(acc.z, off, 64);
        acc.w += __shfl_xor(acc.w, off, 64);
    }
    if (lane < 4) {
        float o = (lane == 0) ? acc.x : (lane == 1) ? acc.y : (lane == 2) ? acc.z : acc.w;
        int ix = r >> 9;
        int iz = r & (NZ - 1);
        out[lane * NROWS + iz * NX + ix] = o;
    }
}

extern "C" void kernel_launch(void* const* d_in, const int* in_sizes, int n_in,
                              void* d_out, int out_size, void* d_ws, size_t ws_size,
                              hipStream_t stream) {
    const float* x        = (const float*)d_in[0];
    const float* csr_vals = (const float*)d_in[1];
    const int*   csr_rows = (const int*)d_in[2];   // int32 per harness contract
    const int*   csr_cols = (const int*)d_in[3];
    float* out = (float*)d_out;
    int nnz = in_sizes[1];

    size_t need = (size_t)NCOLS * sizeof(Half4);   // 2MB
    if (ws_size >= need) {
        Half4* rhs = (Half4*)d_ws;
        (void)hipMemsetAsync(out, 0, (size_t)out_size * sizeof(float), stream);
        pack_rhs_kernel<<<(NCOLS + 255) / 256, 256, 0, stream>>>(x, rhs);
        int nblocks = (nnz + 4 * WAVE_NNZ - 1) / (4 * WAVE_NNZ);   // 4096 blocks, 16K waves
        spmm_seg_kernel<<<nblocks, 256, 0, stream>>>(csr_vals, csr_cols, csr_rows,
                                                     rhs, out, nnz);
    } else {
        spmm_direct_kernel<<<NROWS / 4, 256, 0, stream>>>(x, csr_vals, csr_rows, csr_cols, nnz, out);
    }
}